// Round 17
// baseline (334.901 us; speedup 1.0000x reference)
//
#include <hip/hip_runtime.h>
#include <stdint.h>

#define NHEADS 8
#define NTOK   3137
#define BATCH  16
#define CDIM   512
#define MT     (BATCH*NTOK)   // 50192

typedef unsigned short u16;
typedef float f32x4  __attribute__((ext_vector_type(4)));
typedef short bf16x8 __attribute__((ext_vector_type(8)));

__device__ __forceinline__ float bf2f(u16 u){
  union { uint32_t i; float f; } x; x.i = ((uint32_t)u) << 16; return x.f;
}
__device__ __forceinline__ u16 f2bf(float f){
  union { float f; uint32_t i; } x; x.f = f;
  uint32_t r = x.i + 0x7fffu + ((x.i >> 16) & 1u);
  return (u16)(r >> 16);
}
__device__ __forceinline__ void async_ld16(void* lds, const void* g){
  __builtin_amdgcn_global_load_lds((const __attribute__((address_space(1))) void*)g,
                                   (__attribute__((address_space(3))) void*)lds, 16, 0, 0);
}
#define BARM()   asm volatile("s_barrier" ::: "memory")
#define WAITV(N) asm volatile("s_waitcnt vmcnt(" #N ")" ::: "memory")
#define MFMA16(d,a,b) d = __builtin_amdgcn_mfma_f32_16x16x32_bf16(a,b,d,0,0,0)

// ---------------- K0: fp32 -> bf16 cast ----------------
__global__ void cvt_kernel(const float* __restrict__ src, u16* __restrict__ dst, int n4){
  int i = blockIdx.x * blockDim.x + threadIdx.x;
  if (i < n4){
    float4 v = ((const float4*)src)[i];
    uint32_t lo = ((uint32_t)f2bf(v.y) << 16) | f2bf(v.x);
    uint32_t hi = ((uint32_t)f2bf(v.w) << 16) | f2bf(v.z);
    ((uint2*)dst)[i] = make_uint2(lo, hi);
  }
}

// ---------------- tiny: zero page for OOB conv rows ----------------
__global__ void zero_fill(uint4* p, int n16){
  int i = blockIdx.x * blockDim.x + threadIdx.x;
  if (i < n16) p[i] = make_uint4(0u,0u,0u,0u);
}

// ---------------- qkv GEMM: m97-structure 128x128 single-buffer (round-11 winner, ~110us) ----------------
__global__ __launch_bounds__(256) void gemmM(
    const u16* __restrict__ A, const u16* __restrict__ Bw, const float* __restrict__ bias,
    u16* __restrict__ q_s, u16* __restrict__ k_s, u16* __restrict__ v_s, int M)
{
  __shared__ __align__(16) u16 smem[256*64];   // 32 KiB
  const int t = threadIdx.x;
  const int w = t >> 6, l = t & 63;
  const int wr = w >> 1, wc = w & 1;
  const int lr = l & 15, lg = l >> 4;

  const int nx = gridDim.x;
  const int nwg = nx * gridDim.y;
  const int orig = blockIdx.y * nx + blockIdx.x;
  const int q8 = nwg >> 3, r8 = nwg & 7;
  const int xcd = orig & 7;
  const int wgid = (xcd < r8 ? xcd*(q8+1) : r8*(q8+1) + (xcd-r8)*q8) + (orig >> 3);
  const int n0 = (wgid % nx) * 128;
  const int m0 = (wgid / nx) * 128;

  f32x4 acc[4][4];
#pragma unroll
  for (int i=0;i<4;i++)
#pragma unroll
    for (int j=0;j<4;j++) acc[i][j] = (f32x4){0.f,0.f,0.f,0.f};

  u16* da = smem;
  u16* db = smem + 128*64;

  for (int kt = 0; kt < 8; ++kt){
    const int k0 = kt*64;
#pragma unroll
    for (int j=0;j<4;j++){
      int qc = t + 256*j;
      int R = qc >> 3, c = qc & 7;
      int cs = (c ^ (R & 7)) * 8;
      int ar = m0 + R; if (ar > M-1) ar = M-1;
      async_ld16(&da[qc*8], &A[(size_t)ar*512 + k0 + cs]);
    }
#pragma unroll
    for (int j=0;j<4;j++){
      int qc = t + 256*j;
      int R = qc >> 3, c = qc & 7;
      int cs = (c ^ (R & 7)) * 8;
      async_ld16(&db[qc*8], &Bw[(size_t)(n0+R)*512 + k0 + cs]);
    }
    WAITV(0);
    BARM();
    __builtin_amdgcn_s_setprio(1);
#pragma unroll
    for (int ks=0; ks<2; ks++){
      bf16x8 af[4], bfv[4];
      int chunk = ks*4 + lg;
#pragma unroll
      for (int fi=0;fi<4;fi++){
        int row = wr*64 + fi*16 + lr;
        af[fi] = *(const bf16x8*)&da[row*64 + ((chunk ^ (row & 7))*8)];
      }
#pragma unroll
      for (int fj=0;fj<4;fj++){
        int col = wc*64 + fj*16 + lr;
        bfv[fj] = *(const bf16x8*)&db[col*64 + ((chunk ^ (col & 7))*8)];
      }
#pragma unroll
      for (int fi=0;fi<4;fi++)
#pragma unroll
        for (int fj=0;fj<4;fj++)
          acc[fi][fj] = __builtin_amdgcn_mfma_f32_16x16x32_bf16(af[fi], bfv[fj], acc[fi][fj], 0, 0, 0);
    }
    __builtin_amdgcn_s_setprio(0);
    BARM();
  }

  float bvv[4];
#pragma unroll
  for (int fj=0;fj<4;fj++) bvv[fj] = bias[n0 + wc*64 + fj*16 + lr];
  const int colo = n0 + wc*64;

  u16* warea = smem + w * 4096;
#pragma unroll
  for (int fi=0;fi<4;fi++)
#pragma unroll
    for (int fj=0;fj<4;fj++)
#pragma unroll
      for (int r=0;r<4;r++)
        warea[(fi*16 + lg*4 + r)*64 + fj*16 + lr] = f2bf(acc[fi][fj][r] + bvv[fj]);
  const int part = colo >> 9;
  const int hq   = (colo >> 6) & 7;
  u16* dst = (part == 0) ? q_s : ((part == 1) ? k_s : v_s);
  const int rsub = l >> 3;
  const int csub = (l & 7) * 8;
#pragma unroll
  for (int pass=0; pass<8; ++pass){
    int rl = pass*8 + rsub;
    int m = m0 + wr*64 + rl;
    if (m < M){
      int bb = m / NTOK;
      int n  = m - bb*NTOK;
      uint4 vv = *(const uint4*)&warea[rl*64 + csub];
      *(uint4*)&dst[((size_t)(bb*8 + hq)*NTOK + n)*64 + csub] = vv;
    }
  }
}

// ---------------- proj GEMM: 2-phase double-buffered 256x256 ----------------
__global__ __launch_bounds__(512, 2) void gemmP(
    const u16* __restrict__ A, const u16* __restrict__ Bw, const float* __restrict__ bias,
    float* __restrict__ outF, int M)
{
  constexpr int BM=256, BN=256, WN=4;
  constexpr int THREADS = 512;
  constexpr int MF = 8, NF = 4;
  constexpr int WROWS = 128, WCOLS = 64;
  __shared__ __align__(16) u16 smem[2*(BM+BN)*64];   // 128 KiB

  const int t = threadIdx.x;
  const int w = t >> 6, l = t & 63;
  const int wr = w / WN, wc = w % WN;
  const int lr = l & 15, lg = l >> 4;

  const int nx = gridDim.x;
  const int nwg = nx * gridDim.y;
  const int orig = blockIdx.y * nx + blockIdx.x;
  const int q8 = nwg >> 3, r8 = nwg & 7;
  const int xcd = orig & 7;
  const int wgid = (xcd < r8 ? xcd*(q8+1) : r8*(q8+1) + (xcd-r8)*q8) + (orig >> 3);
  const int n0 = (wgid % nx) * BN;
  const int m0 = (wgid / nx) * BM;

  f32x4 acc[MF][NF];
#pragma unroll
  for (int i=0;i<MF;i++)
#pragma unroll
    for (int j=0;j<NF;j++) acc[i][j] = (f32x4){0.f,0.f,0.f,0.f};

  auto stage = [&](int bi, int k0){
    u16* da = smem + bi*(BM*64);
    u16* db = smem + 2*BM*64 + bi*(BN*64);
#pragma unroll
    for (int j=0;j<(BM*8)/THREADS;j++){
      int qc = t + THREADS*j;
      int R = qc >> 3, c = qc & 7;
      int cs = (c ^ (R & 7)) * 8;
      int ar = m0 + R; if (ar > M-1) ar = M-1;
      async_ld16(&da[qc*8], &A[(size_t)ar*512 + k0 + cs]);
    }
#pragma unroll
    for (int j=0;j<(BN*8)/THREADS;j++){
      int qc = t + THREADS*j;
      int R = qc >> 3, c = qc & 7;
      int cs = (c ^ (R & 7)) * 8;
      async_ld16(&db[qc*8], &Bw[(size_t)(n0+R)*512 + k0 + cs]);
    }
  };

  stage(0, 0);
  __syncthreads();
  int cur = 0;
  for (int kt = 0; kt < 8; ++kt){
    if (kt < 7) stage(cur ^ 1, (kt+1)*64);
    const u16* a_base = smem + cur*(BM*64);
    const u16* b_base = smem + 2*BM*64 + cur*(BN*64);
    __builtin_amdgcn_s_setprio(1);
#pragma unroll
    for (int ks=0; ks<2; ks++){
      bf16x8 af[MF], bfv[NF];
      int chunk = ks*4 + lg;
#pragma unroll
      for (int fi=0;fi<MF;fi++){
        int row = wr*WROWS + fi*16 + lr;
        af[fi] = *(const bf16x8*)&a_base[row*64 + ((chunk ^ (row & 7))*8)];
      }
#pragma unroll
      for (int fj=0;fj<NF;fj++){
        int col = wc*WCOLS + fj*16 + lr;
        bfv[fj] = *(const bf16x8*)&b_base[col*64 + ((chunk ^ (col & 7))*8)];
      }
#pragma unroll
      for (int fi=0;fi<MF;fi++)
#pragma unroll
        for (int fj=0;fj<NF;fj++)
          acc[fi][fj] = __builtin_amdgcn_mfma_f32_16x16x32_bf16(af[fi], bfv[fj], acc[fi][fj], 0, 0, 0);
    }
    __builtin_amdgcn_s_setprio(0);
    __syncthreads();
    cur ^= 1;
  }

  float bvv[NF];
#pragma unroll
  for (int fj=0;fj<NF;fj++) bvv[fj] = bias[n0 + wc*WCOLS + fj*16 + lr];

  constexpr int PR = WROWS/2;
  float* warea = (float*)smem + w * (PR*WCOLS);
  const int colo = n0 + wc*WCOLS;
  const int rsub = l >> 4;
  const int csub = (l & 15) * 4;
#pragma unroll
  for (int p=0; p<2; ++p){
#pragma unroll
    for (int fh=0; fh<MF/2; fh++){
      int fi = p*(MF/2) + fh;
#pragma unroll
      for (int fj=0;fj<NF;fj++)
#pragma unroll
        for (int r=0;r<4;r++)
          warea[(fh*16 + lg*4 + r)*WCOLS + fj*16 + lr] = acc[fi][fj][r] + bvv[fj];
    }
#pragma unroll
    for (int pass=0; pass<PR/4; ++pass){
      int rl = pass*4 + rsub;
      int m = m0 + wr*WROWS + p*PR + rl;
      if (m < M){
        float4 vv = *(const float4*)&warea[rl*WCOLS + csub];
        *(float4*)&outF[(size_t)m*512 + colo + csub] = vv;
      }
    }
  }
}

// ---------------- K2: kv partial via MFMA, 8-way n-split, software-prefetched ----------------
__global__ __launch_bounds__(256) void kv_mfma(
    const u16* __restrict__ k_s, const u16* __restrict__ v_s,
    float* __restrict__ kv_p, float* __restrict__ s_p)
{
  __shared__ __align__(16) u16 ekT[64*64];
  __shared__ __align__(16) u16 vT[64*64];
  __shared__ float part_s[32*64];
  const int t  = threadIdx.x;
  const int bh = blockIdx.x;
  const int qq = blockIdx.y;          // 0..7
  const size_t base = (size_t)bh * NTOK * 64;
  const int c_beg = qq*6 + (qq < 2 ? qq : 2);
  const int c_end = c_beg + 6 + (qq < 2 ? 1 : 0);
  const int w = t >> 6, l = t & 63;
  const int lr = l & 15, lg = l >> 4;
  const int nl0 = t >> 3;
  const int dc  = (t & 7) * 8;

  f32x4 acc[4];
#pragma unroll
  for (int j=0;j<4;j++) acc[j] = (f32x4){0.f,0.f,0.f,0.f};
  float s_loc[8];
#pragma unroll
  for (int i=0;i<8;i++) s_loc[i] = 0.f;

  auto LD = [&](int ch, int half, uint4& kv, uint4& vv){
    int n = ch*64 + nl0 + half*32;
    if (n < NTOK){
      kv = *(const uint4*)&k_s[base + (size_t)n*64 + dc];
      vv = *(const uint4*)&v_s[base + (size_t)n*64 + dc];
    } else {
      kv = make_uint4(0u,0u,0u,0u);
      vv = make_uint4(0u,0u,0u,0u);
    }
  };

  uint4 kc0, vc0, kc1, vc1, kn0, vn0, kn1, vn1;
  LD(c_beg, 0, kc0, vc0);
  LD(c_beg, 1, kc1, vc1);

  for (int ch = c_beg; ch < c_end; ++ch){
    const int n0c = ch*64;
    if (ch + 1 < c_end){ LD(ch+1, 0, kn0, vn0); LD(ch+1, 1, kn1, vn1); }
    __syncthreads();
#pragma unroll
    for (int half=0; half<2; ++half){
      const uint4& kvec = half ? kc1 : kc0;
      const uint4& vvec = half ? vc1 : vc0;
      int nloc = nl0 + half*32;
      bool valid = (n0c + nloc < NTOK);
      const u16* kp = (const u16*)&kvec;
      const u16* vp = (const u16*)&vvec;
      const int nc = nloc >> 3, ne = nloc & 7;
#pragma unroll
      for (int i=0;i<8;i++){
        float e = valid ? __expf(bf2f(kp[i])) : 0.f;
        s_loc[i] += e;
        int row = dc + i;
        int pos = row*64 + ((nc ^ (row & 7) ^ ((row >> 3) & 7))*8) + ne;
        ekT[pos] = f2bf(e);
        vT[pos]  = vp[i];
      }
    }
    __syncthreads();
    __builtin_amdgcn_s_setprio(1);
#pragma unroll
    for (int ks=0; ks<2; ks++){
      int chnk = ks*4 + lg;
      int arow = w*16 + lr;
      bf16x8 af = *(const bf16x8*)&ekT[arow*64 + ((chnk ^ (arow & 7) ^ ((arow >> 3) & 7))*8)];
#pragma unroll
      for (int fj=0; fj<4; fj++){
        int col = fj*16 + lr;
        bf16x8 bv = *(const bf16x8*)&vT[col*64 + ((chnk ^ (col & 7) ^ ((col >> 3) & 7))*8)];
        MFMA16(acc[fj], af, bv);
      }
    }
    __builtin_amdgcn_s_setprio(0);
    kc0 = kn0; vc0 = vn0; kc1 = kn1; vc1 = vn1;
  }

  const size_t obase = ((size_t)qq*128 + bh) * 4096;
#pragma unroll
  for (int fj=0; fj<4; fj++)
#pragma unroll
    for (int r=0; r<4; r++)
      kv_p[obase + (size_t)(w*16 + lg*4 + r)*64 + fj*16 + lr] = acc[fj][r];

#pragma unroll
  for (int i=0;i<8;i++) part_s[nl0*64 + dc + i] = s_loc[i];
  __syncthreads();
  if (t < 64){
    float s = 0.f;
    for (int r=0;r<32;r++) s += part_s[r*64 + t];
    s_p[((size_t)qq*128 + bh)*64 + t] = s;
  }
}

// ---------------- K2b: combine 8 partials + fused fa0, 4-way d-split ----------------
__global__ void kv_reduce(const float* __restrict__ kv_p, const float* __restrict__ s_p,
                          const u16* __restrict__ q_s, u16* __restrict__ kvT,
                          u16* __restrict__ out_pre){
  __shared__ float red[64*16];
  const int bh = blockIdx.x, dq = blockIdx.y, t = threadIdx.x;
  const int b = bh >> 3, h = bh & 7;
  const int k = t >> 2;
  const float q0 = bf2f(q_s[(size_t)bh*NTOK*64 + k]);
  float S = 0.f;
#pragma unroll
  for (int hf=0; hf<8; hf++) S += s_p[(hf*128 + bh)*64 + k];
  const float rS = 1.f / S;
#pragma unroll
  for (int i=0;i<4;i++){
    int dsub = (t & 3)*4 + i;
    int d = dq*16 + dsub;
    int e = k*64 + d;
    float v = 0.f;
#pragma unroll
    for (int hf=0; hf<8; hf++) v += kv_p[(size_t)(hf*128 + bh)*4096 + e];
    float val = v * rS;
    kvT[(size_t)bh*4096 + d*64 + k] = f2bf(val);
    red[k*16 + dsub] = val * q0;
  }
  __syncthreads();
  if (t < 16){
    float s = 0.f;
    for (int r=0;r<64;r++) s += red[r*16 + t];
    out_pre[((size_t)b*NTOK)*CDIM + h*64 + dq*16 + t] = f2bf(0.125f * s);
  }
}

// ---------------- K3: fused depthwise conv + factor_att — 512 threads (8 waves), async staging ----------------
// Same arithmetic/layouts as the round-16 winner; work decomposition widened to 8 waves
// (2x resident waves at identical LDS footprint, half the per-wave serial tail).
// fa MFMA: wave w handles rows (w&3)*16, column half (w>>2). Conv: xg=t>>6, 7 outputs/thread.
template<int R>
__global__ __launch_bounds__(512) void conv_fa(
    const u16* __restrict__ v_s, const u16* __restrict__ q_s,
    const u16* __restrict__ kvT, const u16* __restrict__ zpage,
    const float* __restrict__ wsrc, const float* __restrict__ bsrc,
    int h0, u16* __restrict__ out_pre)
{
  constexpr int KK = 2*R + 1;
  constexpr int TAPS = KK*KK;
  __shared__ __align__(16) u16 smem[8192 + KK*3584];
  u16* vt = smem + 8192;
  const int t = threadIdx.x;
  const int y  = blockIdx.x;
  const int hh = blockIdx.y;
  const int b  = blockIdx.z;
  const int h  = h0 + hh;
  const int bh = b*8 + h;
  const size_t base = (size_t)bh * NTOK * 64;
  const int n0 = 1 + y*56;

  // q + kvT async staging: exactly 1 chunk per thread (64 rows x 8 chunks = 512)
  {
    int row = t >> 3, c = t & 7;
    int cs = (c ^ (row & 7)) * 8;
    int n = n0 + row; if (n > NTOK-1) n = NTOK-1;
    async_ld16(&smem[t*8], &q_s[base + (size_t)n*64 + cs]);
    async_ld16(&smem[4096 + t*8], &kvT[(size_t)bh*4096 + row*64 + cs]);
  }
  // v window async staging (linear dest; OOB rows from zero page); 448 loads/row
#pragma unroll
  for (int ry=0; ry<KK; ry++){
    int yy = y - R + ry;
    const u16* src = (yy >= 0 && yy < 56) ? &v_s[base + (size_t)(1 + yy*56)*64] : zpage;
    if (t < 448) async_ld16(&vt[ry*3584 + t*8], &src[(size_t)t*8]);
  }
  __syncthreads();

  const int w8 = t >> 6, l = t & 63;
  const int lr = l & 15, lg = l >> 4;
  const int rw4 = w8 & 3;            // row band of fa tile
  const int fjb = (w8 >> 2) * 2;     // column half: fj in {fjb, fjb+1}
  f32x4 fac[2];
#pragma unroll
  for (int j=0;j<2;j++) fac[j] = (f32x4){0.f,0.f,0.f,0.f};
#pragma unroll
  for (int ks=0; ks<2; ks++){
    int chunk = ks*4 + lg;
    int arow = rw4*16 + lr;
    bf16x8 af = *(const bf16x8*)&smem[arow*64 + ((chunk ^ (arow & 7))*8)];
#pragma unroll
    for (int fj=0; fj<2; fj++){
      int col = (fjb + fj)*16 + lr;
      bf16x8 bvv = *(const bf16x8*)&smem[4096 + col*64 + ((chunk ^ (col & 7))*8)];
      MFMA16(fac[fj], af, bvv);
    }
  }

  const int d = l;
  const int xg = w8;                 // 0..7, 7 x-positions each
  float wreg[TAPS];
#pragma unroll
  for (int i=0;i<TAPS;i++) wreg[i] = wsrc[(hh*64 + d)*TAPS + i];
  const float bias = bsrc[hh*64 + d];
  float creg[7];
#pragma unroll
  for (int i=0;i<7;i++) creg[i] = bias;
  const int x0 = xg * 7;
#pragma unroll
  for (int ry=0; ry<KK; ry++){
    float rw[7 + 2*R];
#pragma unroll
    for (int i=0; i<7+2*R; i++){
      int xx = x0 - R + i;
      rw[i] = (xx >= 0 && xx < 56) ? bf2f(vt[ry*3584 + xx*64 + d]) : 0.f;
    }
#pragma unroll
    for (int xi=0; xi<7; xi++)
#pragma unroll
      for (int rx=0; rx<KK; rx++)
        creg[xi] += rw[xi+rx] * wreg[ry*KK + rx];
  }

  float qv[7];
#pragma unroll
  for (int xi=0; xi<7; xi++){
    int row = x0 + xi;
    int chunk = d >> 3, e = d & 7;
    qv[xi] = bf2f(smem[row*64 + ((chunk ^ (row & 7))*8) + e]);
  }

  __syncthreads();
  float* fa = (float*)smem;          // overlay [64][64] f32
#pragma unroll
  for (int fj=0; fj<2; fj++)
#pragma unroll
    for (int r=0; r<4; r++)
      fa[(rw4*16 + lg*4 + r)*64 + (fjb + fj)*16 + lr] = 0.125f * fac[fj][r];
  __syncthreads();

#pragma unroll
  for (int xi=0; xi<7; xi++){
    int nn = n0 + x0 + xi;
    out_pre[((size_t)b*NTOK + nn)*CDIM + h*64 + d] =
        f2bf(fa[(x0 + xi)*64 + d] + creg[xi]*qv[xi]);
  }
}

extern "C" void kernel_launch(void* const* d_in, const int* in_sizes, int n_in,
                              void* d_out, int out_size, void* d_ws, size_t ws_size,
                              hipStream_t stream)
{
  const float* x      = (const float*)d_in[0];
  const float* qkv_w  = (const float*)d_in[1];
  const float* qkv_b  = (const float*)d_in[2];
  const float* proj_w = (const float*)d_in[3];
  const float* proj_b = (const float*)d_in[4];
  const float* w3 = (const float*)d_in[5];
  const float* b3 = (const float*)d_in[6];
  const float* w5 = (const float*)d_in[7];
  const float* b5 = (const float*)d_in[8];
  const float* w7 = (const float*)d_in[9];
  const float* b7 = (const float*)d_in[10];
  float* out = (float*)d_out;

  char* ws = (char*)d_ws;
  size_t off = 0;
  auto alloc = [&](size_t bytes) -> void* {
    void* p = ws + off;
    off += (bytes + 255) & ~(size_t)255;
    return p;
  };
  u16*   x_bf     = (u16*)alloc((size_t)MT*512*2);        // reused as out_pre after qkv GEMM
  u16*   qkvw_bf  = (u16*)alloc((size_t)1536*512*2);
  u16*   projw_bf = (u16*)alloc((size_t)512*512*2);
  u16*   q_s      = (u16*)alloc((size_t)128*NTOK*64*2);
  u16*   k_s      = (u16*)alloc((size_t)128*NTOK*64*2);
  u16*   v_s      = (u16*)alloc((size_t)128*NTOK*64*2);
  u16*   kvT      = (u16*)alloc((size_t)128*4096*2);
  float* kv_p     = (float*)alloc((size_t)8*128*4096*4);
  float* s_p      = (float*)alloc((size_t)8*128*64*4);
  u16*   zpage    = (u16*)alloc((size_t)3584*2);
  u16*   out_pre  = x_bf;

  zero_fill<<<2, 256, 0, stream>>>((uint4*)zpage, 448);
  { int n4 = (MT*512)/4;   cvt_kernel<<<(n4+255)/256, 256, 0, stream>>>(x, x_bf, n4); }
  { int n4 = (1536*512)/4; cvt_kernel<<<(n4+255)/256, 256, 0, stream>>>(qkv_w, qkvw_bf, n4); }
  { int n4 = (512*512)/4;  cvt_kernel<<<(n4+255)/256, 256, 0, stream>>>(proj_w, projw_bf, n4); }

  // qkv: M=50192, N=1536, K=512 — 128x128 m97-structure (round-11 winner)
  gemmM<<<dim3(12, 393), 256, 0, stream>>>(x_bf, qkvw_bf, qkv_b, q_s, k_s, v_s, MT);

  kv_mfma<<<dim3(128, 8), 256, 0, stream>>>(k_s, v_s, kv_p, s_p);
  kv_reduce<<<dim3(128, 4), 256, 0, stream>>>(kv_p, s_p, q_s, kvT, out_pre);

  conv_fa<1><<<dim3(56, 2, 16), 512, 0, stream>>>(v_s, q_s, kvT, zpage, w3, b3, 0, out_pre);
  conv_fa<2><<<dim3(56, 3, 16), 512, 0, stream>>>(v_s, q_s, kvT, zpage, w5, b5, 2, out_pre);
  conv_fa<3><<<dim3(56, 3, 16), 512, 0, stream>>>(v_s, q_s, kvT, zpage, w7, b7, 5, out_pre);

  // proj: M=50192, N=512, K=512 — 256x256 2-phase double-buffer
  gemmP<<<dim3(2, 197), 512, 0, stream>>>(out_pre, projw_bf, proj_b, out, MT);
}

// Round 18
// 321.623 us; speedup vs baseline: 1.0413x; 1.0413x over previous
//
#include <hip/hip_runtime.h>
#include <stdint.h>

#define NHEADS 8
#define NTOK   3137
#define BATCH  16
#define CDIM   512
#define MT     (BATCH*NTOK)   // 50192

typedef unsigned short u16;
typedef float f32x4  __attribute__((ext_vector_type(4)));
typedef short bf16x8 __attribute__((ext_vector_type(8)));

__device__ __forceinline__ float bf2f(u16 u){
  union { uint32_t i; float f; } x; x.i = ((uint32_t)u) << 16; return x.f;
}
__device__ __forceinline__ u16 f2bf(float f){
  union { float f; uint32_t i; } x; x.f = f;
  uint32_t r = x.i + 0x7fffu + ((x.i >> 16) & 1u);
  return (u16)(r >> 16);
}
__device__ __forceinline__ void async_ld16(void* lds, const void* g){
  __builtin_amdgcn_global_load_lds((const __attribute__((address_space(1))) void*)g,
                                   (__attribute__((address_space(3))) void*)lds, 16, 0, 0);
}
#define BARM()   asm volatile("s_barrier" ::: "memory")
#define WAITV(N) asm volatile("s_waitcnt vmcnt(" #N ")" ::: "memory")
#define MFMA16(d,a,b) d = __builtin_amdgcn_mfma_f32_16x16x32_bf16(a,b,d,0,0,0)

// ---------------- K0: fp32 -> bf16 cast ----------------
__global__ void cvt_kernel(const float* __restrict__ src, u16* __restrict__ dst, int n4){
  int i = blockIdx.x * blockDim.x + threadIdx.x;
  if (i < n4){
    float4 v = ((const float4*)src)[i];
    uint32_t lo = ((uint32_t)f2bf(v.y) << 16) | f2bf(v.x);
    uint32_t hi = ((uint32_t)f2bf(v.w) << 16) | f2bf(v.z);
    ((uint2*)dst)[i] = make_uint2(lo, hi);
  }
}

// ---------------- tiny: zero page for OOB conv rows ----------------
__global__ void zero_fill(uint4* p, int n16){
  int i = blockIdx.x * blockDim.x + threadIdx.x;
  if (i < n16) p[i] = make_uint4(0u,0u,0u,0u);
}

// ---------------- qkv GEMM: m97-structure 128x128 single-buffer (round-11 winner, ~110us) ----------------
__global__ __launch_bounds__(256) void gemmM(
    const u16* __restrict__ A, const u16* __restrict__ Bw, const float* __restrict__ bias,
    u16* __restrict__ q_s, u16* __restrict__ k_s, u16* __restrict__ v_s, int M)
{
  __shared__ __align__(16) u16 smem[256*64];   // 32 KiB
  const int t = threadIdx.x;
  const int w = t >> 6, l = t & 63;
  const int wr = w >> 1, wc = w & 1;
  const int lr = l & 15, lg = l >> 4;

  const int nx = gridDim.x;
  const int nwg = nx * gridDim.y;
  const int orig = blockIdx.y * nx + blockIdx.x;
  const int q8 = nwg >> 3, r8 = nwg & 7;
  const int xcd = orig & 7;
  const int wgid = (xcd < r8 ? xcd*(q8+1) : r8*(q8+1) + (xcd-r8)*q8) + (orig >> 3);
  const int n0 = (wgid % nx) * 128;
  const int m0 = (wgid / nx) * 128;

  f32x4 acc[4][4];
#pragma unroll
  for (int i=0;i<4;i++)
#pragma unroll
    for (int j=0;j<4;j++) acc[i][j] = (f32x4){0.f,0.f,0.f,0.f};

  u16* da = smem;
  u16* db = smem + 128*64;

  for (int kt = 0; kt < 8; ++kt){
    const int k0 = kt*64;
#pragma unroll
    for (int j=0;j<4;j++){
      int qc = t + 256*j;
      int R = qc >> 3, c = qc & 7;
      int cs = (c ^ (R & 7)) * 8;
      int ar = m0 + R; if (ar > M-1) ar = M-1;
      async_ld16(&da[qc*8], &A[(size_t)ar*512 + k0 + cs]);
    }
#pragma unroll
    for (int j=0;j<4;j++){
      int qc = t + 256*j;
      int R = qc >> 3, c = qc & 7;
      int cs = (c ^ (R & 7)) * 8;
      async_ld16(&db[qc*8], &Bw[(size_t)(n0+R)*512 + k0 + cs]);
    }
    WAITV(0);
    BARM();
    __builtin_amdgcn_s_setprio(1);
#pragma unroll
    for (int ks=0; ks<2; ks++){
      bf16x8 af[4], bfv[4];
      int chunk = ks*4 + lg;
#pragma unroll
      for (int fi=0;fi<4;fi++){
        int row = wr*64 + fi*16 + lr;
        af[fi] = *(const bf16x8*)&da[row*64 + ((chunk ^ (row & 7))*8)];
      }
#pragma unroll
      for (int fj=0;fj<4;fj++){
        int col = wc*64 + fj*16 + lr;
        bfv[fj] = *(const bf16x8*)&db[col*64 + ((chunk ^ (col & 7))*8)];
      }
#pragma unroll
      for (int fi=0;fi<4;fi++)
#pragma unroll
        for (int fj=0;fj<4;fj++)
          acc[fi][fj] = __builtin_amdgcn_mfma_f32_16x16x32_bf16(af[fi], bfv[fj], acc[fi][fj], 0, 0, 0);
    }
    __builtin_amdgcn_s_setprio(0);
    BARM();
  }

  float bvv[4];
#pragma unroll
  for (int fj=0;fj<4;fj++) bvv[fj] = bias[n0 + wc*64 + fj*16 + lr];
  const int colo = n0 + wc*64;

  u16* warea = smem + w * 4096;
#pragma unroll
  for (int fi=0;fi<4;fi++)
#pragma unroll
    for (int fj=0;fj<4;fj++)
#pragma unroll
      for (int r=0;r<4;r++)
        warea[(fi*16 + lg*4 + r)*64 + fj*16 + lr] = f2bf(acc[fi][fj][r] + bvv[fj]);
  const int part = colo >> 9;
  const int hq   = (colo >> 6) & 7;
  u16* dst = (part == 0) ? q_s : ((part == 1) ? k_s : v_s);
  const int rsub = l >> 3;
  const int csub = (l & 7) * 8;
#pragma unroll
  for (int pass=0; pass<8; ++pass){
    int rl = pass*8 + rsub;
    int m = m0 + wr*64 + rl;
    if (m < M){
      int bb = m / NTOK;
      int n  = m - bb*NTOK;
      uint4 vv = *(const uint4*)&warea[rl*64 + csub];
      *(uint4*)&dst[((size_t)(bb*8 + hq)*NTOK + n)*64 + csub] = vv;
    }
  }
}

// ---------------- proj GEMM: 2-phase double-buffered 256x256 ----------------
__global__ __launch_bounds__(512, 2) void gemmP(
    const u16* __restrict__ A, const u16* __restrict__ Bw, const float* __restrict__ bias,
    float* __restrict__ outF, int M)
{
  constexpr int BM=256, BN=256, WN=4;
  constexpr int THREADS = 512;
  constexpr int MF = 8, NF = 4;
  constexpr int WROWS = 128, WCOLS = 64;
  __shared__ __align__(16) u16 smem[2*(BM+BN)*64];   // 128 KiB

  const int t = threadIdx.x;
  const int w = t >> 6, l = t & 63;
  const int wr = w / WN, wc = w % WN;
  const int lr = l & 15, lg = l >> 4;

  const int nx = gridDim.x;
  const int nwg = nx * gridDim.y;
  const int orig = blockIdx.y * nx + blockIdx.x;
  const int q8 = nwg >> 3, r8 = nwg & 7;
  const int xcd = orig & 7;
  const int wgid = (xcd < r8 ? xcd*(q8+1) : r8*(q8+1) + (xcd-r8)*q8) + (orig >> 3);
  const int n0 = (wgid % nx) * BN;
  const int m0 = (wgid / nx) * BM;

  f32x4 acc[MF][NF];
#pragma unroll
  for (int i=0;i<MF;i++)
#pragma unroll
    for (int j=0;j<NF;j++) acc[i][j] = (f32x4){0.f,0.f,0.f,0.f};

  auto stage = [&](int bi, int k0){
    u16* da = smem + bi*(BM*64);
    u16* db = smem + 2*BM*64 + bi*(BN*64);
#pragma unroll
    for (int j=0;j<(BM*8)/THREADS;j++){
      int qc = t + THREADS*j;
      int R = qc >> 3, c = qc & 7;
      int cs = (c ^ (R & 7)) * 8;
      int ar = m0 + R; if (ar > M-1) ar = M-1;
      async_ld16(&da[qc*8], &A[(size_t)ar*512 + k0 + cs]);
    }
#pragma unroll
    for (int j=0;j<(BN*8)/THREADS;j++){
      int qc = t + THREADS*j;
      int R = qc >> 3, c = qc & 7;
      int cs = (c ^ (R & 7)) * 8;
      async_ld16(&db[qc*8], &Bw[(size_t)(n0+R)*512 + k0 + cs]);
    }
  };

  stage(0, 0);
  __syncthreads();
  int cur = 0;
  for (int kt = 0; kt < 8; ++kt){
    if (kt < 7) stage(cur ^ 1, (kt+1)*64);
    const u16* a_base = smem + cur*(BM*64);
    const u16* b_base = smem + 2*BM*64 + cur*(BN*64);
    __builtin_amdgcn_s_setprio(1);
#pragma unroll
    for (int ks=0; ks<2; ks++){
      bf16x8 af[MF], bfv[NF];
      int chunk = ks*4 + lg;
#pragma unroll
      for (int fi=0;fi<MF;fi++){
        int row = wr*WROWS + fi*16 + lr;
        af[fi] = *(const bf16x8*)&a_base[row*64 + ((chunk ^ (row & 7))*8)];
      }
#pragma unroll
      for (int fj=0;fj<NF;fj++){
        int col = wc*WCOLS + fj*16 + lr;
        bfv[fj] = *(const bf16x8*)&b_base[col*64 + ((chunk ^ (col & 7))*8)];
      }
#pragma unroll
      for (int fi=0;fi<MF;fi++)
#pragma unroll
        for (int fj=0;fj<NF;fj++)
          acc[fi][fj] = __builtin_amdgcn_mfma_f32_16x16x32_bf16(af[fi], bfv[fj], acc[fi][fj], 0, 0, 0);
    }
    __builtin_amdgcn_s_setprio(0);
    __syncthreads();
    cur ^= 1;
  }

  float bvv[NF];
#pragma unroll
  for (int fj=0;fj<NF;fj++) bvv[fj] = bias[n0 + wc*WCOLS + fj*16 + lr];

  constexpr int PR = WROWS/2;
  float* warea = (float*)smem + w * (PR*WCOLS);
  const int colo = n0 + wc*WCOLS;
  const int rsub = l >> 4;
  const int csub = (l & 15) * 4;
#pragma unroll
  for (int p=0; p<2; ++p){
#pragma unroll
    for (int fh=0; fh<MF/2; fh++){
      int fi = p*(MF/2) + fh;
#pragma unroll
      for (int fj=0;fj<NF;fj++)
#pragma unroll
        for (int r=0;r<4;r++)
          warea[(fh*16 + lg*4 + r)*WCOLS + fj*16 + lr] = acc[fi][fj][r] + bvv[fj];
    }
#pragma unroll
    for (int pass=0; pass<PR/4; ++pass){
      int rl = pass*4 + rsub;
      int m = m0 + wr*WROWS + p*PR + rl;
      if (m < M){
        float4 vv = *(const float4*)&warea[rl*WCOLS + csub];
        *(float4*)&outF[(size_t)m*512 + colo + csub] = vv;
      }
    }
  }
}

// ---------------- K2: kv partial via MFMA, 8-way n-split, software-prefetched ----------------
__global__ __launch_bounds__(256) void kv_mfma(
    const u16* __restrict__ k_s, const u16* __restrict__ v_s,
    float* __restrict__ kv_p, float* __restrict__ s_p)
{
  __shared__ __align__(16) u16 ekT[64*64];
  __shared__ __align__(16) u16 vT[64*64];
  __shared__ float part_s[32*64];
  const int t  = threadIdx.x;
  const int bh = blockIdx.x;
  const int qq = blockIdx.y;          // 0..7
  const size_t base = (size_t)bh * NTOK * 64;
  const int c_beg = qq*6 + (qq < 2 ? qq : 2);
  const int c_end = c_beg + 6 + (qq < 2 ? 1 : 0);
  const int w = t >> 6, l = t & 63;
  const int lr = l & 15, lg = l >> 4;
  const int nl0 = t >> 3;
  const int dc  = (t & 7) * 8;

  f32x4 acc[4];
#pragma unroll
  for (int j=0;j<4;j++) acc[j] = (f32x4){0.f,0.f,0.f,0.f};
  float s_loc[8];
#pragma unroll
  for (int i=0;i<8;i++) s_loc[i] = 0.f;

  auto LD = [&](int ch, int half, uint4& kv, uint4& vv){
    int n = ch*64 + nl0 + half*32;
    if (n < NTOK){
      kv = *(const uint4*)&k_s[base + (size_t)n*64 + dc];
      vv = *(const uint4*)&v_s[base + (size_t)n*64 + dc];
    } else {
      kv = make_uint4(0u,0u,0u,0u);
      vv = make_uint4(0u,0u,0u,0u);
    }
  };

  uint4 kc0, vc0, kc1, vc1, kn0, vn0, kn1, vn1;
  LD(c_beg, 0, kc0, vc0);
  LD(c_beg, 1, kc1, vc1);

  for (int ch = c_beg; ch < c_end; ++ch){
    const int n0c = ch*64;
    if (ch + 1 < c_end){ LD(ch+1, 0, kn0, vn0); LD(ch+1, 1, kn1, vn1); }
    __syncthreads();
#pragma unroll
    for (int half=0; half<2; ++half){
      const uint4& kvec = half ? kc1 : kc0;
      const uint4& vvec = half ? vc1 : vc0;
      int nloc = nl0 + half*32;
      bool valid = (n0c + nloc < NTOK);
      const u16* kp = (const u16*)&kvec;
      const u16* vp = (const u16*)&vvec;
      const int nc = nloc >> 3, ne = nloc & 7;
#pragma unroll
      for (int i=0;i<8;i++){
        float e = valid ? __expf(bf2f(kp[i])) : 0.f;
        s_loc[i] += e;
        int row = dc + i;
        int pos = row*64 + ((nc ^ (row & 7) ^ ((row >> 3) & 7))*8) + ne;
        ekT[pos] = f2bf(e);
        vT[pos]  = vp[i];
      }
    }
    __syncthreads();
    __builtin_amdgcn_s_setprio(1);
#pragma unroll
    for (int ks=0; ks<2; ks++){
      int chnk = ks*4 + lg;
      int arow = w*16 + lr;
      bf16x8 af = *(const bf16x8*)&ekT[arow*64 + ((chnk ^ (arow & 7) ^ ((arow >> 3) & 7))*8)];
#pragma unroll
      for (int fj=0; fj<4; fj++){
        int col = fj*16 + lr;
        bf16x8 bv = *(const bf16x8*)&vT[col*64 + ((chnk ^ (col & 7) ^ ((col >> 3) & 7))*8)];
        MFMA16(acc[fj], af, bv);
      }
    }
    __builtin_amdgcn_s_setprio(0);
    kc0 = kn0; vc0 = vn0; kc1 = kn1; vc1 = vn1;
  }

  const size_t obase = ((size_t)qq*128 + bh) * 4096;
#pragma unroll
  for (int fj=0; fj<4; fj++)
#pragma unroll
    for (int r=0; r<4; r++)
      kv_p[obase + (size_t)(w*16 + lg*4 + r)*64 + fj*16 + lr] = acc[fj][r];

#pragma unroll
  for (int i=0;i<8;i++) part_s[nl0*64 + dc + i] = s_loc[i];
  __syncthreads();
  if (t < 64){
    float s = 0.f;
    for (int r=0;r<32;r++) s += part_s[r*64 + t];
    s_p[((size_t)qq*128 + bh)*64 + t] = s;
  }
}

// ---------------- K2b: combine 8 partials + fused fa0, 4-way d-split ----------------
__global__ void kv_reduce(const float* __restrict__ kv_p, const float* __restrict__ s_p,
                          const u16* __restrict__ q_s, u16* __restrict__ kvT,
                          u16* __restrict__ out_pre){
  __shared__ float red[64*16];
  const int bh = blockIdx.x, dq = blockIdx.y, t = threadIdx.x;
  const int b = bh >> 3, h = bh & 7;
  const int k = t >> 2;
  const float q0 = bf2f(q_s[(size_t)bh*NTOK*64 + k]);
  float S = 0.f;
#pragma unroll
  for (int hf=0; hf<8; hf++) S += s_p[(hf*128 + bh)*64 + k];
  const float rS = 1.f / S;
#pragma unroll
  for (int i=0;i<4;i++){
    int dsub = (t & 3)*4 + i;
    int d = dq*16 + dsub;
    int e = k*64 + d;
    float v = 0.f;
#pragma unroll
    for (int hf=0; hf<8; hf++) v += kv_p[(size_t)(hf*128 + bh)*4096 + e];
    float val = v * rS;
    kvT[(size_t)bh*4096 + d*64 + k] = f2bf(val);
    red[k*16 + dsub] = val * q0;
  }
  __syncthreads();
  if (t < 16){
    float s = 0.f;
    for (int r=0;r<64;r++) s += red[r*16 + t];
    out_pre[((size_t)b*NTOK)*CDIM + h*64 + dq*16 + t] = f2bf(0.125f * s);
  }
}

// ---------------- K3: fused depthwise conv + factor_att (round-16 winner: 256 thr, async staging) ----------------
template<int R>
__global__ __launch_bounds__(256) void conv_fa(
    const u16* __restrict__ v_s, const u16* __restrict__ q_s,
    const u16* __restrict__ kvT, const u16* __restrict__ zpage,
    const float* __restrict__ wsrc, const float* __restrict__ bsrc,
    int h0, u16* __restrict__ out_pre)
{
  constexpr int KK = 2*R + 1;
  constexpr int TAPS = KK*KK;
  __shared__ __align__(16) u16 smem[8192 + KK*3584];
  u16* vt = smem + 8192;
  const int t = threadIdx.x;
  const int y  = blockIdx.x;
  const int hh = blockIdx.y;
  const int b  = blockIdx.z;
  const int h  = h0 + hh;
  const int bh = b*8 + h;
  const size_t base = (size_t)bh * NTOK * 64;
  const int n0 = 1 + y*56;

#pragma unroll
  for (int j=0;j<2;j++){
    int qq = t + 256*j;
    int row = qq >> 3, c = qq & 7;
    int cs = (c ^ (row & 7)) * 8;
    int n = n0 + row; if (n > NTOK-1) n = NTOK-1;
    async_ld16(&smem[qq*8], &q_s[base + (size_t)n*64 + cs]);
    async_ld16(&smem[4096 + qq*8], &kvT[(size_t)bh*4096 + row*64 + cs]);
  }
#pragma unroll
  for (int ry=0; ry<KK; ry++){
    int yy = y - R + ry;
    const u16* src = (yy >= 0 && yy < 56) ? &v_s[base + (size_t)(1 + yy*56)*64] : zpage;
    for (int idx = t; idx < 448; idx += 256)
      async_ld16(&vt[ry*3584 + idx*8], &src[(size_t)idx*8]);
  }
  __syncthreads();

  const int w = t >> 6, l = t & 63;
  const int lr = l & 15, lg = l >> 4;
  f32x4 fac[4];
#pragma unroll
  for (int j=0;j<4;j++) fac[j] = (f32x4){0.f,0.f,0.f,0.f};
#pragma unroll
  for (int ks=0; ks<2; ks++){
    int chunk = ks*4 + lg;
    int arow = w*16 + lr;
    bf16x8 af = *(const bf16x8*)&smem[arow*64 + ((chunk ^ (arow & 7))*8)];
#pragma unroll
    for (int fj=0; fj<4; fj++){
      int col = fj*16 + lr;
      bf16x8 bvv = *(const bf16x8*)&smem[4096 + col*64 + ((chunk ^ (col & 7))*8)];
      MFMA16(fac[fj], af, bvv);
    }
  }

  const int d = l;
  const int xg = w;
  float wreg[TAPS];
#pragma unroll
  for (int i=0;i<TAPS;i++) wreg[i] = wsrc[(hh*64 + d)*TAPS + i];
  const float bias = bsrc[hh*64 + d];
  float creg[14];
#pragma unroll
  for (int i=0;i<14;i++) creg[i] = bias;
  const int x0 = xg * 14;
#pragma unroll
  for (int ry=0; ry<KK; ry++){
    float rw[14 + 2*R];
#pragma unroll
    for (int i=0; i<14+2*R; i++){
      int xx = x0 - R + i;
      rw[i] = (xx >= 0 && xx < 56) ? bf2f(vt[ry*3584 + xx*64 + d]) : 0.f;
    }
#pragma unroll
    for (int xi=0; xi<14; xi++)
#pragma unroll
      for (int rx=0; rx<KK; rx++)
        creg[xi] += rw[xi+rx] * wreg[ry*KK + rx];
  }

  float qv[14];
#pragma unroll
  for (int xi=0; xi<14; xi++){
    int row = x0 + xi;
    int chunk = d >> 3, e = d & 7;
    qv[xi] = bf2f(smem[row*64 + ((chunk ^ (row & 7))*8) + e]);
  }

  __syncthreads();
  float* fa = (float*)smem;
#pragma unroll
  for (int fj=0; fj<4; fj++)
#pragma unroll
    for (int r=0; r<4; r++)
      fa[(w*16 + lg*4 + r)*64 + fj*16 + lr] = 0.125f * fac[fj][r];
  __syncthreads();

#pragma unroll
  for (int xi=0; xi<14; xi++){
    int nn = n0 + x0 + xi;
    out_pre[((size_t)b*NTOK + nn)*CDIM + h*64 + d] =
        f2bf(fa[(x0 + xi)*64 + d] + creg[xi]*qv[xi]);
  }
}

extern "C" void kernel_launch(void* const* d_in, const int* in_sizes, int n_in,
                              void* d_out, int out_size, void* d_ws, size_t ws_size,
                              hipStream_t stream)
{
  const float* x      = (const float*)d_in[0];
  const float* qkv_w  = (const float*)d_in[1];
  const float* qkv_b  = (const float*)d_in[2];
  const float* proj_w = (const float*)d_in[3];
  const float* proj_b = (const float*)d_in[4];
  const float* w3 = (const float*)d_in[5];
  const float* b3 = (const float*)d_in[6];
  const float* w5 = (const float*)d_in[7];
  const float* b5 = (const float*)d_in[8];
  const float* w7 = (const float*)d_in[9];
  const float* b7 = (const float*)d_in[10];
  float* out = (float*)d_out;

  char* ws = (char*)d_ws;
  size_t off = 0;
  auto alloc = [&](size_t bytes) -> void* {
    void* p = ws + off;
    off += (bytes + 255) & ~(size_t)255;
    return p;
  };
  u16*   x_bf     = (u16*)alloc((size_t)MT*512*2);        // reused as out_pre after qkv GEMM
  u16*   qkvw_bf  = (u16*)alloc((size_t)1536*512*2);
  u16*   projw_bf = (u16*)alloc((size_t)512*512*2);
  u16*   q_s      = (u16*)alloc((size_t)128*NTOK*64*2);
  u16*   k_s      = (u16*)alloc((size_t)128*NTOK*64*2);
  u16*   v_s      = (u16*)alloc((size_t)128*NTOK*64*2);
  u16*   kvT      = (u16*)alloc((size_t)128*4096*2);
  float* kv_p     = (float*)alloc((size_t)8*128*4096*4);
  float* s_p      = (float*)alloc((size_t)8*128*64*4);
  u16*   zpage    = (u16*)alloc((size_t)3584*2);
  u16*   out_pre  = x_bf;

  zero_fill<<<2, 256, 0, stream>>>((uint4*)zpage, 448);
  { int n4 = (MT*512)/4;   cvt_kernel<<<(n4+255)/256, 256, 0, stream>>>(x, x_bf, n4); }
  { int n4 = (1536*512)/4; cvt_kernel<<<(n4+255)/256, 256, 0, stream>>>(qkv_w, qkvw_bf, n4); }
  { int n4 = (512*512)/4;  cvt_kernel<<<(n4+255)/256, 256, 0, stream>>>(proj_w, projw_bf, n4); }

  // qkv: M=50192, N=1536, K=512 — 128x128 m97-structure (round-11 winner)
  gemmM<<<dim3(12, 393), 256, 0, stream>>>(x_bf, qkvw_bf, qkv_b, q_s, k_s, v_s, MT);

  kv_mfma<<<dim3(128, 8), 256, 0, stream>>>(k_s, v_s, kv_p, s_p);
  kv_reduce<<<dim3(128, 4), 256, 0, stream>>>(kv_p, s_p, q_s, kvT, out_pre);

  conv_fa<1><<<dim3(56, 2, 16), 256, 0, stream>>>(v_s, q_s, kvT, zpage, w3, b3, 0, out_pre);
  conv_fa<2><<<dim3(56, 3, 16), 256, 0, stream>>>(v_s, q_s, kvT, zpage, w5, b5, 2, out_pre);
  conv_fa<3><<<dim3(56, 3, 16), 256, 0, stream>>>(v_s, q_s, kvT, zpage, w7, b7, 5, out_pre);

  // proj: M=50192, N=512, K=512 — 256x256 2-phase double-buffer
  gemmP<<<dim3(2, 197), 512, 0, stream>>>(out_pre, projw_bf, proj_b, out, MT);
}